// Round 6
// baseline (214.554 us; speedup 1.0000x reference)
//
#include <hip/hip_runtime.h>

// Bilinear backward warp, NCHW f32 — LDS-tiled gather, ONE barrier per block.
// Block = (tile 64x32, channel-group of 4). Stage 4 halo'd planes (80x48)
// into LDS with coalesced float4 loads, one __syncthreads, then gather
// 2048 px x 4 ch from LDS (ds_read2_b32 pairs) and store coalesced.
// cg = bid&7 aligns channel-group with XCD (round-robin dispatch) so each
// XCD streams its own planes; halo re-reads hit that XCD's L2.
// R1 failed with 64 barriers/block @ 4 blocks/CU; this has 1 barrier and
// 8192 blocks, 2 resident/CU, stage of one hides under gather of the other.

#define TSX 64
#define TSY 32
#define RAD 8
#define LW  80          // TSX + 2*RAD
#define LH  48          // TSY + 2*RAD
#define PLANE (LW*LH)   // 3840 floats = 15360 B
#define CG  4
#define NTHREADS 512

struct __attribute__((packed, aligned(4))) f2u { float lo, hi; };

__global__ __launch_bounds__(NTHREADS, 4) void warp_lds4(
    const float* __restrict__ img,
    const float* __restrict__ flow,
    const int* __restrict__ Hp,
    const int* __restrict__ Wp,
    float* __restrict__ out,
    int HW, int C, int NCG)
{
    __shared__ __align__(16) float lds[CG * PLANE];

    const int W = *Wp;
    const int H = *Hp;
    const int tilesX = (W + TSX - 1) / TSX;
    const int tilesY = (H + TSY - 1) / TSY;
    const int ntiles = tilesX * tilesY;

    const int cg = blockIdx.x % NCG;      // == XCD id under %8 round-robin
    const int t  = blockIdx.x / NCG;      // raster tile index
    if (t >= ntiles) return;

    const int tileY = t / tilesX;
    const int tileX = t - tileY * tilesX;
    const int gx0 = tileX * TSX - RAD;
    const int gy0 = tileY * TSY - RAD;

    const int tid = threadIdx.x;
    const int lx  = tid & 63;             // column within tile
    const int wv  = tid >> 6;             // wave 0..7 -> rows wv*4..wv*4+3

    const int c0 = cg * CG;
    const int nc = min(CG, C - c0);       // channels in this group

    const float Wm1 = (float)(W - 1);
    const float Hm1 = (float)(H - 1);
    const int gx = tileX * TSX + lx;

    // ---- per-pixel precompute: folded weights + LDS pair offset ----
    float w0[4], w1[4], w2[4], w3[4];
    int   enc[4];   // la | dy<<12 ; -1 = global fallback; -2 = out of image
    #pragma unroll
    for (int k = 0; k < 4; ++k) {
        const int gy = tileY * TSY + wv * 4 + k;
        if (gx >= W || gy >= H) { enc[k] = -2; continue; }
        const int pix = gy * W + gx;
        const float u = flow[pix];
        const float v = flow[HW + pix];

        // reference's normalize/denormalize round-trip, op-for-op
        float x = (float)gx + u;
        float y = (float)gy + v;
        x = 2.0f * (x / Wm1 - 0.5f);
        y = 2.0f * (y / Hm1 - 0.5f);
        x = (x + 1.0f) * 0.5f * Wm1;
        y = (y + 1.0f) * 0.5f * Hm1;

        const float x0 = floorf(x), x1 = x0 + 1.0f;
        const float y0 = floorf(y), y1 = y0 + 1.0f;

        const int x0c = (int)fminf(fmaxf(x0, 0.0f), Wm1);
        const int x1c = (int)fminf(fmaxf(x1, 0.0f), Wm1);
        const int y0c = (int)fminf(fmaxf(y0, 0.0f), Hm1);
        const int y1c = (int)fminf(fmaxf(y1, 0.0f), Hm1);

        const float wa = (x1 - x) * (y1 - y);
        const float wb = (x1 - x) * (y - y0);
        const float wc = (x - x0) * (y1 - y);
        const float wd = (x - x0) * (y - y0);

        const int pb = min(x0c, W - 2);   // pair base: covers {x0c,x1c}
        w0[k] = (x0c == pb ? wa : 0.0f) + (x1c == pb ? wc : 0.0f);  // top lo
        w1[k] = (x0c != pb ? wa : 0.0f) + (x1c != pb ? wc : 0.0f);  // top hi
        w2[k] = (x0c == pb ? wb : 0.0f) + (x1c == pb ? wd : 0.0f);  // bot lo
        w3[k] = (x0c != pb ? wb : 0.0f) + (x1c != pb ? wd : 0.0f);  // bot hi

        const int lxp = pb - gx0;
        const int ly0 = y0c - gy0;
        const int ly1 = y1c - gy0;
        if (lxp >= 0 && lxp + 1 < LW && ly0 >= 0 && ly1 < LH) {
            enc[k] = (ly0 * LW + lxp) | ((ly1 - ly0) << 12);
        } else {
            enc[k] = -1;  // out-of-halo flow tail: global fallback
        }
    }

    // ---- stage nc halo'd planes into LDS ----
    const bool xint = (gx0 >= 0) && (gx0 + LW <= W) && ((W & 3) == 0);
    if (xint) {
        const int NV = LH * (LW / 4);     // 960 float4 groups per plane
        for (int i = tid; i < nc * NV; i += NTHREADS) {
            const int ch  = i / NV;
            const int rem = i - ch * NV;
            const int r   = rem / (LW / 4);
            const int g   = rem - r * (LW / 4);
            const int yy  = min(max(gy0 + r, 0), H - 1);
            const float4 v4 = *(const float4*)(img + (size_t)(c0 + ch) * HW
                                               + (size_t)yy * W + (gx0 + 4 * g));
            *(float4*)&lds[ch * PLANE + r * LW + 4 * g] = v4;
        }
    } else {
        for (int i = tid; i < nc * PLANE; i += NTHREADS) {
            const int ch  = i / PLANE;
            const int rem = i - ch * PLANE;
            const int r   = rem / LW;
            const int cc  = rem - r * LW;
            const int yy  = min(max(gy0 + r, 0), H - 1);
            const int xx  = min(max(gx0 + cc, 0), W - 1);
            lds[i] = img[(size_t)(c0 + ch) * HW + (size_t)yy * W + xx];
        }
    }

    __syncthreads();

    // ---- gather from LDS + blend + store ----
    #pragma unroll
    for (int k = 0; k < 4; ++k) {
        const int e = enc[k];
        if (e == -2) continue;
        const int gy  = tileY * TSY + wv * 4 + k;
        const int pix = gy * W + gx;

        if (__builtin_expect(e >= 0, 1)) {
            const int la  = e & 4095;
            const int dyo = ((e >> 12) & 1) * LW;
            #pragma unroll
            for (int c = 0; c < CG; ++c) {
                if (c >= nc) break;
                const int b = c * PLANE + la;
                const float lt = lds[b],        ht = lds[b + 1];
                const float lb = lds[b + dyo],  hb = lds[b + dyo + 1];
                out[(size_t)(c0 + c) * HW + pix] =
                    w0[k] * lt + w1[k] * ht + w2[k] * lb + w3[k] * hb;
            }
        } else {
            // rare out-of-halo: full recompute + global gather
            const float u = flow[pix];
            const float v = flow[HW + pix];
            float x = (float)gx + u;
            float y = (float)gy + v;
            x = 2.0f * (x / Wm1 - 0.5f);
            y = 2.0f * (y / Hm1 - 0.5f);
            x = (x + 1.0f) * 0.5f * Wm1;
            y = (y + 1.0f) * 0.5f * Hm1;
            const float x0 = floorf(x), y0f = floorf(y);
            const int x0c = (int)fminf(fmaxf(x0, 0.0f), Wm1);
            const int x1c = (int)fminf(fmaxf(x0 + 1.0f, 0.0f), Wm1);
            const int y0c = (int)fminf(fmaxf(y0f, 0.0f), Hm1);
            const int y1c = (int)fminf(fmaxf(y0f + 1.0f, 0.0f), Hm1);
            const float wa = (x0 + 1.0f - x) * (y0f + 1.0f - y);
            const float wb = (x0 + 1.0f - x) * (y - y0f);
            const float wc = (x - x0) * (y0f + 1.0f - y);
            const float wd = (x - x0) * (y - y0f);
            for (int c = 0; c < nc; ++c) {
                const float* ic = img + (size_t)(c0 + c) * HW;
                const float Ia = ic[(size_t)y0c * W + x0c];
                const float Ib = ic[(size_t)y1c * W + x0c];
                const float Ic = ic[(size_t)y0c * W + x1c];
                const float Id = ic[(size_t)y1c * W + x1c];
                out[(size_t)(c0 + c) * HW + pix] = wa*Ia + wb*Ib + wc*Ic + wd*Id;
            }
        }
    }
}

extern "C" void kernel_launch(void* const* d_in, const int* in_sizes, int n_in,
                              void* d_out, int out_size, void* d_ws, size_t ws_size,
                              hipStream_t stream) {
    const float* img  = (const float*)d_in[0];
    const float* flow = (const float*)d_in[1];
    const int*   Hp   = (const int*)d_in[2];
    const int*   Wp   = (const int*)d_in[3];
    float* out = (float*)d_out;

    const int HW = in_sizes[1] / 2;    // flow is (1,2,H,W)
    const int C  = in_sizes[0] / HW;   // img is (1,C,H,W)
    const int NCG = (C + CG - 1) / CG;

    // host doesn't know W,H (device scalars): launch with tile slack,
    // excess blocks exit on the in-kernel ntiles guard.
    const int maxt = (HW + TSX * TSY - 1) / (TSX * TSY) + 1024;
    const int grid = maxt * NCG;
    warp_lds4<<<grid, NTHREADS, 0, stream>>>(img, flow, Hp, Wp, out, HW, C, NCG);
}